// Round 11
// baseline (41.379 us; speedup 1.0000x reference)
//
#include <hip/hip_runtime.h>

// SpatialMTP1Hop (R11): zero-shuffle err_node.
// Ledger (R2 direct PMC): err_node ~25-27us = 3x HBM roofline; every prior
// variant used 15 cross-lane ops per 2 nodes (ds_bpermute chains + LDS pipe)
// plus scattered 12B target reads / 4B err writes. R11 err: per-thread-node,
// H staged per 32-col chunk into column-major LDS [32][257] (2-way banks =
// free) via coalesced float4 loads, register double-buffered (issue-early/
// write-late); dot products accumulate IN-LANE (zero shuffles); W via
// wave-uniform unrolled offsets (s_load); target/err accesses coalesced.
// Edge phase: R10's block-local counting sort (256 thr). Exact u64 fixed-point.

#define CNT_SHIFT 44
#define ERR_SCALE 67108864.0f     // 2^26 fixed-point for err
#define BKT_SHIFT 8
#define BKT_SIZE  256
#define P2B       256             // bucketize blocks
#define BTHR      256
#define STASH     6272            // u32 per block region (>= chunk edges 6252)
#define PREF_STRIDE 200           // u16 slots per source block (NB+1 <= 200)
#define SMEM_BYTES 32896          // max(err 32*257*4, bkt 27140)

__device__ __forceinline__ int owner_fn(int s, bool fast, int C,
                                        const int* __restrict__ arr_idx,
                                        const int* __restrict__ centers) {
    if (fast) return (s < C) ? s : -1;
    int i = arr_idx[s];
    return ((unsigned)i < (unsigned)C && centers[i] == s) ? i : -1;
}

// D1: center scatter + per-block arange validation + out zeroing.
__global__ __launch_bounds__(256)
void prep_kernel(const int* __restrict__ centers,
                 int* __restrict__ arr_idx,
                 int* __restrict__ flagpart,
                 float* __restrict__ out,
                 int C, int out_size) {
    __shared__ int ok;
    int t = threadIdx.x;
    int gtid = blockIdx.x * 256 + t;
    if (t == 0) ok = 1;
    __syncthreads();
    bool mism = false;
    if (gtid < C) {
        int c = centers[gtid];
        arr_idx[c] = gtid;                 // scatter-only, no sentinel needed
        mism = (c != gtid);
    }
    if (__ballot(mism) != 0ull && (t & 63) == 0) atomicAnd(&ok, 0);
    __syncthreads();
    if (t == 0) flagpart[blockIdx.x] = ok;
    if (gtid < out_size) out[gtid] = 0.f;
}

// D2: blocks [0,P2B): counting-sort bucketize; blocks [P2B,..): err_node.
__global__ __launch_bounds__(BTHR)
void mid_kernel(const float* __restrict__ H, const float* __restrict__ W,
                const float* __restrict__ b, const float* __restrict__ target,
                const int* __restrict__ eidx, const int* __restrict__ centers,
                const int* __restrict__ arr_idx,
                const int* __restrict__ flagpart,
                float* __restrict__ err_node,
                unsigned short* __restrict__ pref_g,
                unsigned int* __restrict__ pairs,
                int N, int E, int C, int NB, int NBV) {
    __shared__ __align__(16) unsigned char smem_raw[SMEM_BYTES];
    const int t = threadIdx.x;

    if (blockIdx.x < P2B) {
        // ------------- bucketize (block-local counting sort) -------------
        unsigned int* stash = (unsigned int*)smem_raw;             // 25088 B
        unsigned int* hist  = (unsigned int*)(smem_raw + 25088);   // 1024 B
        unsigned int* scan  = (unsigned int*)(smem_raw + 26112);   // 1024 B
        int*          okf   = (int*)(smem_raw + 27136);
        if (t == 0) *okf = 1;
        hist[t] = 0u;
        __syncthreads();
        bool my_ok = (t < NBV) ? (flagpart[t] != 0) : true;
        if (__ballot(!my_ok) != 0ull && (t & 63) == 0) atomicAnd(okf, 0);
        __syncthreads();
        const bool fast = (*okf != 0);

        const int E4     = E >> 2;                    // (E&3)==0 host-gated
        const int chunk4 = (E4 + P2B - 1) / P2B;
        const int c0     = blockIdx.x * chunk4;
        const int c1     = min(E4, c0 + chunk4);
        const int4* r0 = reinterpret_cast<const int4*>(eidx);
        const int4* r1 = reinterpret_cast<const int4*>(eidx + E);

        for (int i = c0 + t; i < c1; i += BTHR) {
            int4 s4 = r0[i];
            int ss[4] = {s4.x, s4.y, s4.z, s4.w};
            #pragma unroll
            for (int k = 0; k < 4; ++k) {
                int o = owner_fn(ss[k], fast, C, arr_idx, centers);
                if (o >= 0) atomicAdd(&hist[(unsigned)o >> BKT_SHIFT], 1u);
            }
        }
        __syncthreads();
        scan[t] = hist[t];
        __syncthreads();
        for (int off = 1; off < 256; off <<= 1) {
            unsigned v = (t >= off) ? scan[t - off] : 0u;
            __syncthreads();
            if (t >= off) scan[t] += v;
            __syncthreads();
        }
        {
            unsigned pre = (t == 0) ? 0u : scan[t - 1];
            hist[t] = pre;                               // cursor
            if (t <= NB)
                pref_g[(size_t)blockIdx.x * PREF_STRIDE + t] = (unsigned short)pre;
        }
        __syncthreads();
        for (int i = c0 + t; i < c1; i += BTHR) {
            int4 s4 = r0[i];
            int4 d4 = r1[i];
            int ss[4] = {s4.x, s4.y, s4.z, s4.w};
            int dd[4] = {d4.x, d4.y, d4.z, d4.w};
            #pragma unroll
            for (int k = 0; k < 4; ++k) {
                int o = owner_fn(ss[k], fast, C, arr_idx, centers);
                if (o >= 0) {
                    unsigned bk = (unsigned)o >> BKT_SHIFT;
                    unsigned pos = atomicAdd(&hist[bk], 1u);
                    stash[pos] = (((unsigned)o & (BKT_SIZE - 1)) << 17)
                               | (unsigned)dd[k];
                }
            }
        }
        __syncthreads();
        uint4*       dg = reinterpret_cast<uint4*>(pairs + (size_t)blockIdx.x * STASH);
        const uint4* sg = reinterpret_cast<const uint4*>(stash);
        for (int i = t; i < STASH / 4; i += BTHR) dg[i] = sg[i];
    } else {
        // ------------- err_node: per-thread node, LDS-staged, 0 shuffles -------------
        float* lh = (float*)smem_raw;                  // [32][257] col-major
        const int  base  = (blockIdx.x - P2B) * 256;
        const int  node  = base + t;
        const bool alive = (node < N);
        const float4* Hg = reinterpret_cast<const float4*>(H);

        float a0 = 0.f, a1 = 0.f, a2 = 0.f;
        float4 vA[8], vB[8];

        // LOADC(c, v): 8 coalesced float4 loads covering 256 rows x cols [32c,32c+32)
        #define LOADC(c, v)                                                     \
            { _Pragma("unroll")                                                 \
              for (int i = 0; i < 8; ++i) {                                     \
                  int idx = t + 256 * i;                                        \
                  int row = idx >> 3, q = idx & 7;                              \
                  int gn = base + row;                                          \
                  v[i] = (gn < N) ? Hg[(size_t)gn * 32 + (c) * 8 + q]           \
                                  : make_float4(0.f, 0.f, 0.f, 0.f);            \
              } }
        // WRITEC(v): scatter to lds[(4q+j)*257 + row]  (banks ~2-way: free)
        #define WRITEC(v)                                                       \
            { _Pragma("unroll")                                                 \
              for (int i = 0; i < 8; ++i) {                                     \
                  int idx = t + 256 * i;                                        \
                  int row = idx >> 3, q = idx & 7;                              \
                  lh[(4 * q + 0) * 257 + row] = v[i].x;                         \
                  lh[(4 * q + 1) * 257 + row] = v[i].y;                         \
                  lh[(4 * q + 2) * 257 + row] = v[i].z;                         \
                  lh[(4 * q + 3) * 257 + row] = v[i].w;                         \
              } }
        // COMPUTEC(c): in-lane accumulation; W offsets compile-time -> s_load
        #define COMPUTEC(c)                                                     \
            { _Pragma("unroll")                                                 \
              for (int k = 0; k < 32; ++k) {                                    \
                  float hk = lh[k * 257 + t];                                   \
                  a0 += hk * W[((c) * 32 + k) * 3 + 0];                         \
                  a1 += hk * W[((c) * 32 + k) * 3 + 1];                         \
                  a2 += hk * W[((c) * 32 + k) * 3 + 2];                         \
              } }

        LOADC(0, vA)
        __syncthreads(); WRITEC(vA) __syncthreads(); LOADC(1, vB) COMPUTEC(0)
        __syncthreads(); WRITEC(vB) __syncthreads(); LOADC(2, vA) COMPUTEC(1)
        __syncthreads(); WRITEC(vA) __syncthreads(); LOADC(3, vB) COMPUTEC(2)
        __syncthreads(); WRITEC(vB) __syncthreads();              COMPUTEC(3)

        #undef LOADC
        #undef WRITEC
        #undef COMPUTEC

        if (alive) {
            float e0 = a0 + b[0] - target[(size_t)node * 3 + 0];
            float e1 = a1 + b[1] - target[(size_t)node * 3 + 1];
            float e2 = a2 + b[2] - target[(size_t)node * 3 + 2];
            err_node[node] = (e0 * e0 + e1 * e1 + e2 * e2) * (1.0f / 3.0f);
        }
    }
}

// D3: per-bucket reduce. Thread t owns source-block t's segment of bucket bk.
__global__ __launch_bounds__(256)
void reduce_kernel(const unsigned int* __restrict__ pairs,
                   const unsigned short* __restrict__ pref_g,
                   const float* __restrict__ err_node,
                   float* __restrict__ out, int C, float invC) {
    __shared__ unsigned long long bins[BKT_SIZE];
    __shared__ float wsum[4];
    const int bk = blockIdx.x, t = threadIdx.x;
    bins[t] = 0ull;
    __syncthreads();
    {
        const size_t pb = (size_t)t * PREF_STRIDE;
        unsigned start = pref_g[pb + bk];
        unsigned end   = pref_g[pb + bk + 1];
        const unsigned int* reg = pairs + (size_t)t * STASH;
        for (unsigned i = start; i < end; ++i) {
            unsigned p = reg[i];
            float err = err_node[p & 0x1FFFFu];
            atomicAdd(&bins[p >> 17],
                      (1ull << CNT_SHIFT) + (unsigned long long)(err * ERR_SCALE));
        }
    }
    __syncthreads();
    float term = 0.f;
    {
        int center = bk * BKT_SIZE + t;
        if (center < C) {
            unsigned long long u = bins[t];
            float cnt = (float)(u >> CNT_SHIFT);
            float es  = (float)(u & ((1ull << CNT_SHIFT) - 1)) * (1.0f / ERR_SCALE);
            term = es / fmaxf(cnt, 1.0f);
        }
    }
    #pragma unroll
    for (int m = 32; m > 0; m >>= 1) term += __shfl_down(term, m, 64);
    if ((t & 63) == 0) wsum[t >> 6] = term;
    __syncthreads();
    if (t == 0)
        atomicAdd(out, (wsum[0] + wsum[1] + wsum[2] + wsum[3]) * invC);
}

// ================= fallback (general shapes / small ws) =================
__global__ __launch_bounds__(256)
void fb_err_kernel(const float* __restrict__ H, const float* __restrict__ W,
                   const float* __restrict__ b, const float* __restrict__ target,
                   const int* __restrict__ centers,
                   float* __restrict__ err_node, int* __restrict__ arr_idx,
                   float* __restrict__ out, int N, int C, int D, int DO,
                   int out_size) {
    int gtid = blockIdx.x * blockDim.x + threadIdx.x;
    if (gtid < C) arr_idx[centers[gtid]] = gtid;
    if (gtid < out_size) out[gtid] = 0.f;
    if (gtid < N) {
        float acc = 0.f;
        for (int j = 0; j < DO; ++j) {
            float a = b[j];
            for (int r = 0; r < D; ++r)
                a += H[(size_t)gtid * D + r] * W[(size_t)r * DO + j];
            float e = a - target[(size_t)gtid * DO + j];
            acc += e * e;
        }
        err_node[gtid] = acc / (float)DO;
    }
}

__global__ void fb_edge_kernel(const int* __restrict__ eidx,
                               const int* __restrict__ arr_idx,
                               const int* __restrict__ centers,
                               const float* __restrict__ err_node,
                               unsigned long long* __restrict__ binsg,
                               int E, int C) {
    int e = blockIdx.x * blockDim.x + threadIdx.x;
    if (e >= E) return;
    int s = eidx[e];
    int o = owner_fn(s, false, C, arr_idx, centers);
    if (o >= 0) {
        int d = eidx[E + e];
        unsigned long long add = (1ull << CNT_SHIFT)
                               + (unsigned long long)(err_node[d] * ERR_SCALE);
        atomicAdd(&binsg[o], add);
    }
}

__global__ void fb_finalize_kernel(const unsigned long long* __restrict__ binsg,
                                   float* __restrict__ out, int C) {
    int i = blockIdx.x * blockDim.x + threadIdx.x;
    float term = 0.f;
    if (i < C) {
        unsigned long long u = binsg[i];
        float cnt = (float)(u >> CNT_SHIFT);
        float es  = (float)(u & ((1ull << CNT_SHIFT) - 1)) * (1.0f / ERR_SCALE);
        term = es / fmaxf(cnt, 1.0f);
    }
    #pragma unroll
    for (int m = 32; m > 0; m >>= 1) term += __shfl_down(term, m, 64);
    __shared__ float wsum[4];
    if ((threadIdx.x & 63) == 0) wsum[threadIdx.x >> 6] = term;
    __syncthreads();
    if (threadIdx.x == 0)
        atomicAdd(out, (wsum[0] + wsum[1] + wsum[2] + wsum[3]) / (float)C);
}

extern "C" void kernel_launch(void* const* d_in, const int* in_sizes, int n_in,
                              void* d_out, int out_size, void* d_ws, size_t ws_size,
                              hipStream_t stream) {
    const float* H      = (const float*)d_in[0];
    const float* W      = (const float*)d_in[1];
    const float* b      = (const float*)d_in[2];
    const float* target = (const float*)d_in[3];
    const int*   eidx   = (const int*)d_in[4];
    const int*   ctrs   = (const int*)d_in[5];

    const int DO = in_sizes[2];
    const int D  = in_sizes[1] / DO;     // 128
    const int N  = in_sizes[0] / D;      // 100000
    const int E  = in_sizes[4] / 2;      // 1600000
    const int C  = in_sizes[5];          // 50000
    const int NB  = (C + BKT_SIZE - 1) >> BKT_SHIFT;  // 196
    const int NBV = (C + 255) / 256;                  // 196
    const int NERRB = (N + 255) / 256;                // 391

    size_t off = 0;
    auto take = [&](size_t bytes) {
        void* p = (char*)d_ws + off;
        off = (off + bytes + 255) & ~255ull;
        return p;
    };
    float*          err_node = (float*)take((size_t)N * 4);
    int*            arr_idx  = (int*)take((size_t)N * 4);
    int*            flagpart = (int*)take((size_t)NBV * 4);
    unsigned short* pref_g   = (unsigned short*)take((size_t)P2B * PREF_STRIDE * 2);
    unsigned int*   pairs    = (unsigned int*)((char*)d_ws + off);
    size_t need = off + (size_t)P2B * STASH * 4;

    int chunk_edges = 4 * ((E / 4 + P2B - 1) / P2B);
    bool fits = (ws_size >= need) && (NB + 1 <= PREF_STRIDE) && (NBV <= BTHR) &&
                (N < (1 << 17)) && ((E & 3) == 0) && (chunk_edges <= STASH) &&
                (D == 128) && (DO == 3);
    if (fits) {
        prep_kernel<<<NBV, 256, 0, stream>>>(ctrs, arr_idx, flagpart,
                                             (float*)d_out, C, out_size);
        mid_kernel<<<P2B + NERRB, BTHR, 0, stream>>>(H, W, b, target, eidx,
                                                     ctrs, arr_idx, flagpart,
                                                     err_node, pref_g, pairs,
                                                     N, E, C, NB, NBV);
        reduce_kernel<<<NB, 256, 0, stream>>>(pairs, pref_g, err_node,
                                              (float*)d_out, C, 1.0f / (float)C);
    } else {
        unsigned long long* binsg = (unsigned long long*)((char*)d_ws + off);
        hipMemsetAsync(binsg, 0, (size_t)C * 8, stream);
        int thr = 256;
        fb_err_kernel<<<(max(N, C) + thr - 1) / thr, thr, 0, stream>>>(
            H, W, b, target, ctrs, err_node, arr_idx, (float*)d_out,
            N, C, D, DO, out_size);
        fb_edge_kernel<<<(E + thr - 1) / thr, thr, 0, stream>>>(
            eidx, arr_idx, ctrs, err_node, binsg, E, C);
        fb_finalize_kernel<<<(C + thr - 1) / thr, thr, 0, stream>>>(
            binsg, (float*)d_out, C);
    }
}